// Round 3
// baseline (40090.677 us; speedup 1.0000x reference)
//
#include <hip/hip_runtime.h>
#include <cmath>

typedef _Float16 f16;
typedef _Float16 half8 __attribute__((ext_vector_type(8)));
typedef float floatx4 __attribute__((ext_vector_type(4)));

#define NT 512
#define NB 64
#define NH 512
#define NG 2048
#define CHUNK 128

__device__ inline float sigf(float x) { return 1.0f / (1.0f + __expf(-x)); }

__device__ inline void load_lds16(const f16* g, f16* l) {
  __builtin_amdgcn_global_load_lds(
      (__attribute__((address_space(1))) void*)g,
      (__attribute__((address_space(3))) void*)l, 16, 0, 0);
}

// ---------------------------------------------------------------- meta
__global__ void prep_meta(const int* __restrict__ bs_raw, int* __restrict__ lens,
                          int* __restrict__ cum) {
  __shared__ int sbs[NT];
  // batch_sizes may arrive as int64 (stride 2 in int32 view); bs[1]==0 iff int64.
  int stride = (bs_raw[1] == 0) ? 2 : 1;
  for (int i = threadIdx.x; i < NT; i += 256) sbs[i] = bs_raw[i * stride];
  __syncthreads();
  for (int b = threadIdx.x; b < NB; b += 256) {
    int n = 0;
    for (int t = 0; t < NT; ++t) n += (sbs[t] > b);
    lens[b] = n;
  }
  if (threadIdx.x == 0) {
    int run = 0;
    for (int t = 0; t < NT; ++t) { cum[t] = run; run += sbs[t]; }
  }
}

// ---------------------------------------------------------------- unpack
__global__ void scatter_rows(const float* __restrict__ data, const int* __restrict__ pidx,
                             f16* __restrict__ X0) {
  int r = blockIdx.x;
  int row = pidx[r];
  const float* src = data + (size_t)r * 512;
  f16* dst = X0 + (size_t)row * 512;
  for (int k = threadIdx.x; k < 512; k += 256) dst[k] = (f16)src[k];
}

__global__ void f32_to_f16(const float* __restrict__ in, f16* __restrict__ out, size_t n) {
  size_t i = (size_t)blockIdx.x * 256 + threadIdx.x;
  size_t stride = (size_t)gridDim.x * 256;
  for (; i < n; i += stride) out[i] = (f16)in[i];
}

// ---------------------------------------------------------------- per-layer h/c init
__global__ void init_h(const float* __restrict__ h0, const float* __restrict__ c0,
                       float* __restrict__ hsave, float* __restrict__ csave,
                       f16* __restrict__ hbuf, int layer) {
  int idx = blockIdx.x * 256 + threadIdx.x;  // 2*64*512 = 65536 total
  int d = idx >> 15, rem = idx & 32767;      // rem = b*512 + j
  float hv = h0[(size_t)(2 * layer + d) * NB * NH + rem];
  float cv = c0[(size_t)(2 * layer + d) * NB * NH + rem];
  hsave[idx] = hv;
  csave[idx] = cv;
  hbuf[(size_t)d * 2 * NB * NH + rem] = (f16)hv;  // ping buffer 0
}

// ---------------------------------------------------------------- gx GEMM (one chunk)
// gxc[d][ct][b][col] = X[t'(ct,b)] . W[d][col] + bias; t' reversed for dir 1.
__global__ __launch_bounds__(256) void gemm_gx(const f16* __restrict__ A,
                                               const f16* __restrict__ W,
                                               const float* __restrict__ bias,
                                               const int* __restrict__ lens,
                                               f16* __restrict__ gxc, int K, int c0) {
  const int d = blockIdx.z;
  const int m0 = blockIdx.y * 128;  // chunk-local row tile (8192 rows/chunk)
  const int n0 = blockIdx.x * 128;
  const f16* Wd = W + (size_t)d * NG * K;

  __shared__ __align__(16) f16 As[128 * 32];
  __shared__ __align__(16) f16 Bs[128 * 32];

  const int tid = threadIdx.x, lane = tid & 63, wv = tid >> 6;
  const int wm = wv >> 1, wn = wv & 1;
  const int lrow = lane >> 2, lcol = (lane & 3) * 8;
  const int q = lane >> 4, nn = lane & 15;

  const f16* aptr[2];
  const f16* bptr[2];
#pragma unroll
  for (int i = 0; i < 2; ++i) {
    int ch = wv * 2 + i;
    int m = m0 + ch * 16 + lrow;          // chunk-local row = ct*64 + b
    int t = c0 + (m >> 6), b = m & 63;
    int tt = t;
    if (d) { tt = lens[b] - 1 - t; tt = tt < 0 ? 0 : (tt > NT - 1 ? NT - 1 : tt); }
    aptr[i] = A + (size_t)(tt * NB + b) * K + lcol;
    bptr[i] = Wd + (size_t)(n0 + ch * 16 + lrow) * K + lcol;
  }

  floatx4 acc[4][4] = {};
  for (int k0 = 0; k0 < K; k0 += 32) {
    __syncthreads();
#pragma unroll
    for (int i = 0; i < 2; ++i) {
      int ch = wv * 2 + i;
      load_lds16(aptr[i] + k0, As + ch * 512);
      load_lds16(bptr[i] + k0, Bs + ch * 512);
    }
    __syncthreads();
    half8 a[4], b[4];
#pragma unroll
    for (int f = 0; f < 4; ++f) {
      a[f] = *(const half8*)(As + (wm * 64 + f * 16 + nn) * 32 + q * 8);
      b[f] = *(const half8*)(Bs + (wn * 64 + f * 16 + nn) * 32 + q * 8);
    }
#pragma unroll
    for (int fm = 0; fm < 4; ++fm)
#pragma unroll
      for (int fn = 0; fn < 4; ++fn)
        acc[fm][fn] = __builtin_amdgcn_mfma_f32_16x16x32_f16(a[fm], b[fn], acc[fm][fn], 0, 0, 0);
  }

  f16* gxd = gxc + (size_t)d * CHUNK * NB * NG;
#pragma unroll
  for (int fn = 0; fn < 4; ++fn) {
    int col = n0 + wn * 64 + fn * 16 + nn;
    float bv = bias[d * NG + col];
#pragma unroll
    for (int fm = 0; fm < 4; ++fm) {
      int mb = m0 + wm * 64 + fm * 16 + q * 4;
#pragma unroll
      for (int r = 0; r < 4; ++r)
        gxd[(size_t)(mb + r) * NG + col] = (f16)(acc[fm][fn][r] + bv);
    }
  }
}

// ---------------------------------------------------------------- recurrence (one chunk)
// 256 blocks = 8 groups x 32. Group g = (dir = g&1, batch slice = (g>>3 bits)...):
// group blocks {g, g+8, ..., g+248} share one counter (same XCD under round-robin).
// Block w owns j in [w*16, w*16+16); wave wv owns 4 j (16 gate cols) x 16 rows.
__global__ __launch_bounds__(256) void lstm_rec(
    const f16* __restrict__ gxc, const f16* __restrict__ whh,
    const int* __restrict__ lens, const int* __restrict__ cum,
    float* __restrict__ hsave, float* __restrict__ csave,
    f16* __restrict__ hbuf, f16* __restrict__ Y, float* __restrict__ outp,
    float* __restrict__ hT, float* __restrict__ cT,
    int* __restrict__ ctrs, int c0, int mode, int layer) {
  const int tid = threadIdx.x, lane = tid & 63, wv = tid >> 6;
  const int g = blockIdx.x & 7, w = blockIdx.x >> 3;
  const int dir = g & 1, bsl = g >> 1;
  const int q = lane >> 4, nn = lane & 15;

  const int maxlen = lens[bsl * 16];  // rows sorted by length desc
  int nst = maxlen - c0;
  if (nst <= 0) return;               // whole group finished (uniform per group)
  if (nst > CHUNK) nst = CHUNK;

  __shared__ float s_g[4][16][17];

  const int jbase = w * 16 + wv * 4;
  const int coln = (nn >> 2) * NH + jbase + (nn & 3);  // gate (nn>>2), j = jbase+(nn&3)
  const f16* whd = whh + (size_t)dir * NG * NH;
  half8 bf[16];
#pragma unroll
  for (int s = 0; s < 16; ++s)
    bf[s] = *(const half8*)(whd + (size_t)coln * NH + s * 32 + q * 8);

  const int b_e = bsl * 16 + nn;      // cell-update row
  const int jglob = jbase + q;        // cell-update j
  const int lene = lens[b_e];
  const int brow = bsl * 16 + q * 4;  // MFMA acc rows base
  const int lidx = (dir * NB + b_e) * NH + jglob;
  float h = hsave[lidx], c = csave[lidx];

  f16* hb = hbuf + (size_t)dir * 2 * NB * NH;
  const f16* gxd = gxc + (size_t)dir * CHUNK * NB * NG;
  int* ctr = ctrs + g * 64;  // 256B spacing

  for (int ct = 0; ct < nst; ++ct) {
    const int t = c0 + ct;
    const f16* hprev = hb + (t & 1) * NB * NH;
    f16* hnext = hb + ((t + 1) & 1) * NB * NH;
    float gxv[4];
#pragma unroll
    for (int r = 0; r < 4; ++r)
      gxv[r] = (float)gxd[(size_t)(ct * NB + brow + r) * NG + coln];
    floatx4 acc = {0.f, 0.f, 0.f, 0.f};
#pragma unroll
    for (int s = 0; s < 16; ++s) {
      half8 a = *(const half8*)(hprev + (bsl * 16 + nn) * NH + s * 32 + q * 8);
      acc = __builtin_amdgcn_mfma_f32_16x16x32_f16(a, bf[s], acc, 0, 0, 0);
    }
#pragma unroll
    for (int r = 0; r < 4; ++r) s_g[wv][q * 4 + r][nn] = acc[r] + gxv[r];
    __syncthreads();
    const bool act = (t < lene);
    if (act) {
      float gi = s_g[wv][nn][q];
      float gf = s_g[wv][nn][4 + q];
      float gg = s_g[wv][nn][8 + q];
      float go = s_g[wv][nn][12 + q];
      c = sigf(gf) * c + sigf(gi) * tanhf(gg);
      h = sigf(go) * tanhf(c);
    }
    hnext[b_e * NH + jglob] = (f16)h;  // always: frozen rows stay current
    if (mode == 0) {
      int tp = act ? (dir ? (lene - 1 - t) : t) : t;
      Y[(size_t)(tp * NB + b_e) * (2 * NH) + dir * NH + jglob] = act ? (f16)h : (f16)0.f;
    } else if (act) {
      int tp = dir ? (lene - 1 - t) : t;
      outp[(size_t)(cum[tp] + b_e) * (2 * NH) + dir * NH + jglob] = h;
    }
    // ---- group barrier (32 blocks) ----
    __syncthreads();  // drains vmcnt: block's stores are in L2
    if (tid == 0) {
      __hip_atomic_fetch_add(ctr, 1, __ATOMIC_RELEASE, __HIP_MEMORY_SCOPE_AGENT);
      const int target = (ct + 1) * 32;
      int it = 0;
      while (__hip_atomic_load(ctr, __ATOMIC_RELAXED, __HIP_MEMORY_SCOPE_AGENT) < target &&
             it < 1000000) {
        ++it;
        __builtin_amdgcn_s_sleep(1);
      }
    }
    __syncthreads();
    __threadfence();  // agent acquire: invalidate stale L2/L1 lines
  }

  hsave[lidx] = h;
  csave[lidx] = c;
  const int sidx = ((2 * layer + dir) * NB + b_e) * NH + jglob;
  hT[sidx] = h;
  cT[sidx] = c;
}

// ---------------------------------------------------------------- host
extern "C" void kernel_launch(void* const* d_in, const int* in_sizes, int n_in,
                              void* d_out, int out_size, void* d_ws, size_t ws_size,
                              hipStream_t stream) {
  const float* data  = (const float*)d_in[0];
  const float* h0    = (const float*)d_in[1];
  const float* c0    = (const float*)d_in[2];
  const float* w_ih0 = (const float*)d_in[3];
  const float* w_hh0 = (const float*)d_in[4];
  const float* b0    = (const float*)d_in[5];
  const float* w_ihr = (const float*)d_in[6];
  const float* w_hhr = (const float*)d_in[7];
  const float* b_r   = (const float*)d_in[8];
  const int* bs_raw  = (const int*)d_in[9];
  const int* pidx    = (const int*)d_in[10];
  const int nrows = in_sizes[0] / 512;  // 24704 packed rows
  float* out = (float*)d_out;

  // Y0 (layer-0 output, f16, 67MB) lives inside d_out's 101MB packed-out region:
  // its last reader (l1 gemm) strictly precedes the first l2 write to d_out.
  f16* Y0 = (f16*)d_out;
  float* hT = out + (size_t)nrows * 1024;
  float* cT = hT + (size_t)6 * NB * NH;

  char* p = (char*)d_ws;
  auto take = [&](size_t bytes) {
    char* r = p;
    p += (bytes + 255) & ~(size_t)255;
    return (void*)r;
  };
  f16* gxc   = (f16*)take((size_t)2 * CHUNK * NB * NG * 2);  // 67 MB
  f16* Y1    = (f16*)take((size_t)NT * NB * 1024 * 2);       // 67 MB
  f16* X0    = Y1;  // alias: X0 dead after l0 gemm; Y1 first written by l1 rec
  f16* wih16 = (f16*)take((size_t)2 * NG * 1024 * 2);        // 8 MB
  f16* whh16 = (f16*)take((size_t)2 * NG * NH * 2);          // 4 MB
  f16* hbuf  = (f16*)take((size_t)2 * 2 * NB * NH * 2);
  float* hsave = (float*)take((size_t)2 * NB * NH * 4);
  float* csave = (float*)take((size_t)2 * NB * NH * 4);
  int* lens = (int*)take(256);
  int* cum  = (int*)take(NT * 4);
  int* ctrs = (int*)take(8 * 64 * 4);

  prep_meta<<<1, 256, 0, stream>>>(bs_raw, lens, cum);
  (void)hipMemsetAsync(X0, 0, (size_t)NT * NB * 512 * 2, stream);
  scatter_rows<<<nrows, 256, 0, stream>>>(data, pidx, X0);

  for (int l = 0; l < 3; ++l) {
    const float* wih_f = (l == 0) ? w_ih0 : w_ihr + (size_t)(l - 1) * 2 * NG * 1024;
    const float* whh_f = (l == 0) ? w_hh0 : w_hhr + (size_t)(l - 1) * 2 * NG * NH;
    const float* bias  = (l == 0) ? b0 : b_r + (size_t)(l - 1) * 2 * NG;
    const int K = (l == 0) ? 512 : 1024;
    const f16* Xl = (l == 0) ? X0 : ((l == 1) ? Y0 : Y1);
    f16* Yl = (l == 0) ? Y0 : Y1;  // unused for l==2 (writes packed out)
    f32_to_f16<<<256, 256, 0, stream>>>(wih_f, wih16, (size_t)2 * NG * K);
    f32_to_f16<<<256, 256, 0, stream>>>(whh_f, whh16, (size_t)2 * NG * NH);
    init_h<<<256, 256, 0, stream>>>(h0, c0, hsave, csave, hbuf, l);
    for (int c = 0; c < 4; ++c) {
      gemm_gx<<<dim3(16, 64, 2), 256, 0, stream>>>(Xl, wih16, bias, lens, gxc, K, c * CHUNK);
      (void)hipMemsetAsync(ctrs, 0, 8 * 64 * 4, stream);
      lstm_rec<<<256, 256, 0, stream>>>(gxc, whh16, lens, cum, hsave, csave, hbuf, Yl,
                                        out, hT, cT, ctrs, c * CHUNK, (l == 2) ? 1 : 0, l);
    }
  }
}

// Round 4
// 10550.071 us; speedup vs baseline: 3.8000x; 3.8000x over previous
//
#include <hip/hip_runtime.h>
#include <cmath>

typedef _Float16 f16;
typedef _Float16 half8 __attribute__((ext_vector_type(8)));
typedef float floatx4 __attribute__((ext_vector_type(4)));

#define NT 512
#define NB 64
#define NH 512
#define NG 2048
#define CHUNK 128

__device__ inline float sigf(float x) { return 1.0f / (1.0f + __expf(-x)); }
// tanh(x) = 2*sigmoid(2x)-1 (|err| ~1e-7 rel, fine vs 4.5e-2 threshold)
__device__ inline float tanhfast(float x) { return 2.0f / (1.0f + __expf(-2.0f * x)) - 1.0f; }

__device__ inline void load_lds16(const f16* g, f16* l) {
  __builtin_amdgcn_global_load_lds(
      (__attribute__((address_space(1))) void*)g,
      (__attribute__((address_space(3))) void*)l, 16, 0, 0);
}

// Coherent (IF$-path, sc1) accessors: relaxed agent-scope atomics — no fences.
__device__ inline half8 load_h8c(const f16* p) {
  union { unsigned long long u[2]; half8 v; } r;
  r.u[0] = __hip_atomic_load((const unsigned long long*)p, __ATOMIC_RELAXED, __HIP_MEMORY_SCOPE_AGENT);
  r.u[1] = __hip_atomic_load((const unsigned long long*)(p + 4), __ATOMIC_RELAXED, __HIP_MEMORY_SCOPE_AGENT);
  return r.v;
}
__device__ inline void store_hc(f16* p, f16 v) {
  union { f16 f; unsigned short s; } c; c.f = v;
  __hip_atomic_store((unsigned short*)p, c.s, __ATOMIC_RELAXED, __HIP_MEMORY_SCOPE_AGENT);
}

// ---------------------------------------------------------------- meta
__global__ void prep_meta(const int* __restrict__ bs_raw, int* __restrict__ lens,
                          int* __restrict__ cum) {
  __shared__ int sbs[NT];
  int stride = (bs_raw[1] == 0) ? 2 : 1;  // int64 arrives as stride-2 int32
  for (int i = threadIdx.x; i < NT; i += 256) sbs[i] = bs_raw[i * stride];
  __syncthreads();
  for (int b = threadIdx.x; b < NB; b += 256) {
    int n = 0;
    for (int t = 0; t < NT; ++t) n += (sbs[t] > b);
    lens[b] = n;
  }
  if (threadIdx.x == 0) {
    int run = 0;
    for (int t = 0; t < NT; ++t) { cum[t] = run; run += sbs[t]; }
  }
}

// ---------------------------------------------------------------- unpack
__global__ void scatter_rows(const float* __restrict__ data, const int* __restrict__ pidx,
                             f16* __restrict__ X0) {
  int r = blockIdx.x;
  int row = pidx[r];
  const float* src = data + (size_t)r * 512;
  f16* dst = X0 + (size_t)row * 512;
  for (int k = threadIdx.x; k < 512; k += 256) dst[k] = (f16)src[k];
}

__global__ void f32_to_f16(const float* __restrict__ in, f16* __restrict__ out, size_t n) {
  size_t i = (size_t)blockIdx.x * 256 + threadIdx.x;
  size_t stride = (size_t)gridDim.x * 256;
  for (; i < n; i += stride) out[i] = (f16)in[i];
}

// ---------------------------------------------------------------- per-layer h/c init
__global__ void init_h(const float* __restrict__ h0, const float* __restrict__ c0,
                       float* __restrict__ hsave, float* __restrict__ csave,
                       f16* __restrict__ hbuf, int layer) {
  int idx = blockIdx.x * 256 + threadIdx.x;  // 2*64*512 = 65536
  int d = idx >> 15, rem = idx & 32767;
  float hv = h0[(size_t)(2 * layer + d) * NB * NH + rem];
  float cv = c0[(size_t)(2 * layer + d) * NB * NH + rem];
  hsave[idx] = hv;
  csave[idx] = cv;
  hbuf[(size_t)d * 2 * NB * NH + rem] = (f16)hv;  // ping buffer 0
}

// ---------------------------------------------------------------- gx GEMM (one chunk)
__global__ __launch_bounds__(256) void gemm_gx(const f16* __restrict__ A,
                                               const f16* __restrict__ W,
                                               const float* __restrict__ bias,
                                               const int* __restrict__ lens,
                                               f16* __restrict__ gxc, int K, int c0) {
  const int d = blockIdx.z;
  const int m0 = blockIdx.y * 128;
  const int n0 = blockIdx.x * 128;
  const f16* Wd = W + (size_t)d * NG * K;

  __shared__ __align__(16) f16 As[128 * 32];
  __shared__ __align__(16) f16 Bs[128 * 32];

  const int tid = threadIdx.x, lane = tid & 63, wv = tid >> 6;
  const int wm = wv >> 1, wn = wv & 1;
  const int lrow = lane >> 2, lcol = (lane & 3) * 8;
  const int q = lane >> 4, nn = lane & 15;

  const f16* aptr[2];
  const f16* bptr[2];
#pragma unroll
  for (int i = 0; i < 2; ++i) {
    int ch = wv * 2 + i;
    int m = m0 + ch * 16 + lrow;  // chunk-local row = ct*64 + b
    int t = c0 + (m >> 6), b = m & 63;
    int tt = t;
    if (d) { tt = lens[b] - 1 - t; tt = tt < 0 ? 0 : (tt > NT - 1 ? NT - 1 : tt); }
    aptr[i] = A + (size_t)(tt * NB + b) * K + lcol;
    bptr[i] = Wd + (size_t)(n0 + ch * 16 + lrow) * K + lcol;
  }

  floatx4 acc[4][4] = {};
  for (int k0 = 0; k0 < K; k0 += 32) {
    __syncthreads();
#pragma unroll
    for (int i = 0; i < 2; ++i) {
      int ch = wv * 2 + i;
      load_lds16(aptr[i] + k0, As + ch * 512);
      load_lds16(bptr[i] + k0, Bs + ch * 512);
    }
    __syncthreads();
    half8 a[4], b[4];
#pragma unroll
    for (int f = 0; f < 4; ++f) {
      a[f] = *(const half8*)(As + (wm * 64 + f * 16 + nn) * 32 + q * 8);
      b[f] = *(const half8*)(Bs + (wn * 64 + f * 16 + nn) * 32 + q * 8);
    }
#pragma unroll
    for (int fm = 0; fm < 4; ++fm)
#pragma unroll
      for (int fn = 0; fn < 4; ++fn)
        acc[fm][fn] = __builtin_amdgcn_mfma_f32_16x16x32_f16(a[fm], b[fn], acc[fm][fn], 0, 0, 0);
  }

  f16* gxd = gxc + (size_t)d * CHUNK * NB * NG;
#pragma unroll
  for (int fn = 0; fn < 4; ++fn) {
    int col = n0 + wn * 64 + fn * 16 + nn;
    float bv = bias[d * NG + col];
#pragma unroll
    for (int fm = 0; fm < 4; ++fm) {
      int mb = m0 + wm * 64 + fm * 16 + q * 4;
#pragma unroll
      for (int r = 0; r < 4; ++r)
        gxd[(size_t)(mb + r) * NG + col] = (f16)(acc[fm][fn][r] + bv);
    }
  }
}

// ---------------------------------------------------------------- recurrence (one chunk)
// 256 blocks = 8 groups x 32. Group g = (dir=g&1, 16-row slice bsl=g>>1) is CLOSED
// under h dataflow. Sync: per-block epoch flags, written/read via sc1 (IF$) path,
// wave-0 lane-parallel poll. NO fences, NO atomic RMW, NO L2 writeback/invalidate.
__global__ __launch_bounds__(256) void lstm_rec(
    const f16* __restrict__ gxc, const f16* __restrict__ whh,
    const int* __restrict__ lens, const int* __restrict__ cum,
    float* __restrict__ hsave, float* __restrict__ csave,
    f16* __restrict__ hbuf, f16* __restrict__ Y, float* __restrict__ outp,
    float* __restrict__ hT, float* __restrict__ cT,
    int* __restrict__ flags, int c0, int mode, int layer) {
  const int tid = threadIdx.x, lane = tid & 63, wv = tid >> 6;
  const int g = blockIdx.x & 7, w = blockIdx.x >> 3;
  const int dir = g & 1, bsl = g >> 1;
  const int q = lane >> 4, nn = lane & 15;

  const int maxlen = lens[bsl * 16];  // rows sorted desc: uniform group exit
  int nst = maxlen - c0;
  if (nst <= 0) return;
  if (nst > CHUNK) nst = CHUNK;

  __shared__ float s_g[4][16][17];

  const int jbase = w * 16 + wv * 4;
  const int coln = (nn >> 2) * NH + jbase + (nn & 3);
  const f16* whd = whh + (size_t)dir * NG * NH;
  half8 bf[16];
#pragma unroll
  for (int s = 0; s < 16; ++s)
    bf[s] = *(const half8*)(whd + (size_t)coln * NH + s * 32 + q * 8);

  const int b_e = bsl * 16 + nn;
  const int jglob = jbase + q;
  const int lene = lens[b_e];
  const int brow = bsl * 16 + q * 4;
  const int lidx = (dir * NB + b_e) * NH + jglob;
  float h = hsave[lidx], c = csave[lidx];

  f16* hb = hbuf + (size_t)dir * 2 * NB * NH;
  const f16* gxd = gxc + (size_t)dir * CHUNK * NB * NG;
  int* gflag = flags + g * 32;

  const int ebase = layer * NT;  // epoch monotonic across chunks & layers

  for (int ct = 0; ct < nst; ++ct) {
    const int t = c0 + ct;
    const int epoch = ebase + t + 1;
    const f16* hprev = hb + (t & 1) * NB * NH;
    f16* hnext = hb + ((t + 1) & 1) * NB * NH;

    // gx (normal cached loads) + all 16 A-frags (coherent loads), then MFMA
    float gxv[4];
#pragma unroll
    for (int r = 0; r < 4; ++r)
      gxv[r] = (float)gxd[(size_t)(ct * NB + brow + r) * NG + coln];
    half8 a[16];
#pragma unroll
    for (int s = 0; s < 16; ++s)
      a[s] = load_h8c(hprev + (bsl * 16 + nn) * NH + s * 32 + q * 8);
    floatx4 acc0 = {0.f, 0.f, 0.f, 0.f}, acc1 = {0.f, 0.f, 0.f, 0.f};
#pragma unroll
    for (int s = 0; s < 8; ++s) {
      acc0 = __builtin_amdgcn_mfma_f32_16x16x32_f16(a[2 * s], bf[2 * s], acc0, 0, 0, 0);
      acc1 = __builtin_amdgcn_mfma_f32_16x16x32_f16(a[2 * s + 1], bf[2 * s + 1], acc1, 0, 0, 0);
    }
#pragma unroll
    for (int r = 0; r < 4; ++r) s_g[wv][q * 4 + r][nn] = acc0[r] + acc1[r] + gxv[r];
    __syncthreads();

    const bool act = (t < lene);
    if (act) {
      float gi = s_g[wv][nn][q];
      float gf = s_g[wv][nn][4 + q];
      float gg = s_g[wv][nn][8 + q];
      float go = s_g[wv][nn][12 + q];
      c = sigf(gf) * c + sigf(gi) * tanhfast(gg);
      h = sigf(go) * tanhfast(c);
    }
    store_hc(hnext + b_e * NH + jglob, (f16)h);  // coherent h publish
    if (mode == 0) {
      int tp = act ? (dir ? (lene - 1 - t) : t) : t;
      Y[(size_t)(tp * NB + b_e) * (2 * NH) + dir * NH + jglob] = act ? (f16)h : (f16)0.f;
    } else if (act) {
      int tp = dir ? (lene - 1 - t) : t;
      outp[(size_t)(cum[tp] + b_e) * (2 * NH) + dir * NH + jglob] = h;
    }

    // ---- group barrier: flags through IF$, no fences ----
    asm volatile("s_waitcnt vmcnt(0)" ::: "memory");
    __syncthreads();  // every wave drained its stores (compiler adds waitcnt too)
    if (tid == 0)
      __hip_atomic_store(gflag + w, epoch, __ATOMIC_RELAXED, __HIP_MEMORY_SCOPE_AGENT);
    if (wv == 0) {
      int it = 0;
      for (;;) {
        int f = (lane < 32)
                    ? __hip_atomic_load(gflag + lane, __ATOMIC_RELAXED, __HIP_MEMORY_SCOPE_AGENT)
                    : epoch;
        if (~__ballot(f >= epoch) == 0ull) break;
        if (++it > 2000000) break;  // fail as wrong-answer, not hang
      }
    }
    __syncthreads();
  }

  hsave[lidx] = h;
  csave[lidx] = c;
  const int sidx = ((2 * layer + dir) * NB + b_e) * NH + jglob;
  hT[sidx] = h;
  cT[sidx] = c;
}

// ---------------------------------------------------------------- host
extern "C" void kernel_launch(void* const* d_in, const int* in_sizes, int n_in,
                              void* d_out, int out_size, void* d_ws, size_t ws_size,
                              hipStream_t stream) {
  const float* data  = (const float*)d_in[0];
  const float* h0    = (const float*)d_in[1];
  const float* c0    = (const float*)d_in[2];
  const float* w_ih0 = (const float*)d_in[3];
  const float* w_hh0 = (const float*)d_in[4];
  const float* b0    = (const float*)d_in[5];
  const float* w_ihr = (const float*)d_in[6];
  const float* w_hhr = (const float*)d_in[7];
  const float* b_r   = (const float*)d_in[8];
  const int* bs_raw  = (const int*)d_in[9];
  const int* pidx    = (const int*)d_in[10];
  const int nrows = in_sizes[0] / 512;
  float* out = (float*)d_out;

  // Y0 (layer-0 output, f16, 67MB) aliases d_out's 101MB packed-out region.
  f16* Y0 = (f16*)d_out;
  float* hT = out + (size_t)nrows * 1024;
  float* cT = hT + (size_t)6 * NB * NH;

  char* p = (char*)d_ws;
  auto take = [&](size_t bytes) {
    char* r = p;
    p += (bytes + 255) & ~(size_t)255;
    return (void*)r;
  };
  f16* gxc   = (f16*)take((size_t)2 * CHUNK * NB * NG * 2);  // 67 MB
  f16* Y1    = (f16*)take((size_t)NT * NB * 1024 * 2);       // 67 MB
  f16* X0    = Y1;  // alias: X0 dead after l0 gemm; Y1 first written by l1 rec
  f16* wih16 = (f16*)take((size_t)2 * NG * 1024 * 2);
  f16* whh16 = (f16*)take((size_t)2 * NG * NH * 2);
  f16* hbuf  = (f16*)take((size_t)2 * 2 * NB * NH * 2);
  float* hsave = (float*)take((size_t)2 * NB * NH * 4);
  float* csave = (float*)take((size_t)2 * NB * NH * 4);
  int* lens = (int*)take(256);
  int* cum  = (int*)take(NT * 4);
  int* flags = (int*)take(8 * 32 * 4);

  prep_meta<<<1, 256, 0, stream>>>(bs_raw, lens, cum);
  (void)hipMemsetAsync(X0, 0, (size_t)NT * NB * 512 * 2, stream);
  (void)hipMemsetAsync(flags, 0, 8 * 32 * 4, stream);
  scatter_rows<<<nrows, 256, 0, stream>>>(data, pidx, X0);

  for (int l = 0; l < 3; ++l) {
    const float* wih_f = (l == 0) ? w_ih0 : w_ihr + (size_t)(l - 1) * 2 * NG * 1024;
    const float* whh_f = (l == 0) ? w_hh0 : w_hhr + (size_t)(l - 1) * 2 * NG * NH;
    const float* bias  = (l == 0) ? b0 : b_r + (size_t)(l - 1) * 2 * NG;
    const int K = (l == 0) ? 512 : 1024;
    const f16* Xl = (l == 0) ? X0 : ((l == 1) ? Y0 : Y1);
    f16* Yl = (l == 0) ? Y0 : Y1;
    f32_to_f16<<<256, 256, 0, stream>>>(wih_f, wih16, (size_t)2 * NG * K);
    f32_to_f16<<<256, 256, 0, stream>>>(whh_f, whh16, (size_t)2 * NG * NH);
    init_h<<<256, 256, 0, stream>>>(h0, c0, hsave, csave, hbuf, l);
    for (int c = 0; c < 4; ++c) {
      gemm_gx<<<dim3(16, 64, 2), 256, 0, stream>>>(Xl, wih16, bias, lens, gxc, K, c * CHUNK);
      lstm_rec<<<256, 256, 0, stream>>>(gxc, whh16, lens, cum, hsave, csave, hbuf, Yl,
                                        out, hT, cT, flags, c * CHUNK, (l == 2) ? 1 : 0, l);
    }
  }
}

// Round 5
// 8291.406 us; speedup vs baseline: 4.8352x; 1.2724x over previous
//
#include <hip/hip_runtime.h>
#include <cmath>

typedef _Float16 f16;
typedef _Float16 half8 __attribute__((ext_vector_type(8)));
typedef float floatx4 __attribute__((ext_vector_type(4)));
typedef unsigned u32x4 __attribute__((ext_vector_type(4)));

#define NT 512
#define NB 64
#define NH 512
#define NG 2048
#define CHUNK 128

__device__ inline float sigf(float x) { return 1.0f / (1.0f + __expf(-x)); }
__device__ inline float tanhfast(float x) { return 2.0f / (1.0f + __expf(-2.0f * x)) - 1.0f; }

__device__ inline void load_lds16(const f16* g, f16* l) {
  __builtin_amdgcn_global_load_lds(
      (__attribute__((address_space(1))) void*)g,
      (__attribute__((address_space(3))) void*)l, 16, 0, 0);
}

// ---------------------------------------------------------------- meta
__global__ void prep_meta(const int* __restrict__ bs_raw, int* __restrict__ lens,
                          int* __restrict__ cum) {
  __shared__ int sbs[NT];
  int stride = (bs_raw[1] == 0) ? 2 : 1;  // int64 arrives as stride-2 int32
  for (int i = threadIdx.x; i < NT; i += 256) sbs[i] = bs_raw[i * stride];
  __syncthreads();
  for (int b = threadIdx.x; b < NB; b += 256) {
    int n = 0;
    for (int t = 0; t < NT; ++t) n += (sbs[t] > b);
    lens[b] = n;
  }
  if (threadIdx.x == 0) {
    int run = 0;
    for (int t = 0; t < NT; ++t) { cum[t] = run; run += sbs[t]; }
  }
}

// ---------------------------------------------------------------- unpack
__global__ void scatter_rows(const float* __restrict__ data, const int* __restrict__ pidx,
                             f16* __restrict__ X0) {
  int r = blockIdx.x;
  int row = pidx[r];
  const float* src = data + (size_t)r * 512;
  f16* dst = X0 + (size_t)row * 512;
  for (int k = threadIdx.x; k < 512; k += 256) dst[k] = (f16)src[k];
}

__global__ void f32_to_f16(const float* __restrict__ in, f16* __restrict__ out, size_t n) {
  size_t i = (size_t)blockIdx.x * 256 + threadIdx.x;
  size_t stride = (size_t)gridDim.x * 256;
  for (; i < n; i += stride) out[i] = (f16)in[i];
}

// ---------------------------------------------------------------- per-layer h/c init
// Writes tagged h words (epoch = layer*NT) into parity-0 via sc1 (coherent path).
__global__ void init_h(const float* __restrict__ h0, const float* __restrict__ c0,
                       float* __restrict__ hsave, float* __restrict__ csave,
                       unsigned* __restrict__ ht, int layer) {
  int idx = blockIdx.x * 256 + threadIdx.x;  // 2*64*512 = 65536
  int d = idx >> 15, rem = idx & 32767;
  float hv = h0[(size_t)(2 * layer + d) * NB * NH + rem];
  float cv = c0[(size_t)(2 * layer + d) * NB * NH + rem];
  hsave[idx] = hv;
  csave[idx] = cv;
  union { f16 f; unsigned short s; } hc; hc.f = (f16)hv;
  unsigned word = ((unsigned)(layer * NT) << 16) | hc.s;
  __hip_atomic_store(ht + (size_t)d * NB * NH + rem, word,
                     __ATOMIC_RELAXED, __HIP_MEMORY_SCOPE_AGENT);
}

// ---------------------------------------------------------------- gx GEMM (one chunk)
__global__ __launch_bounds__(256) void gemm_gx(const f16* __restrict__ A,
                                               const f16* __restrict__ W,
                                               const float* __restrict__ bias,
                                               const int* __restrict__ lens,
                                               f16* __restrict__ gxc, int K, int c0) {
  const int d = blockIdx.z;
  const int m0 = blockIdx.y * 128;
  const int n0 = blockIdx.x * 128;
  const f16* Wd = W + (size_t)d * NG * K;

  __shared__ __align__(16) f16 As[128 * 32];
  __shared__ __align__(16) f16 Bs[128 * 32];

  const int tid = threadIdx.x, lane = tid & 63, wv = tid >> 6;
  const int wm = wv >> 1, wn = wv & 1;
  const int lrow = lane >> 2, lcol = (lane & 3) * 8;
  const int q = lane >> 4, nn = lane & 15;

  const f16* aptr[2];
  const f16* bptr[2];
#pragma unroll
  for (int i = 0; i < 2; ++i) {
    int ch = wv * 2 + i;
    int m = m0 + ch * 16 + lrow;  // chunk-local row = ct*64 + b
    int t = c0 + (m >> 6), b = m & 63;
    int tt = t;
    if (d) { tt = lens[b] - 1 - t; tt = tt < 0 ? 0 : (tt > NT - 1 ? NT - 1 : tt); }
    aptr[i] = A + (size_t)(tt * NB + b) * K + lcol;
    bptr[i] = Wd + (size_t)(n0 + ch * 16 + lrow) * K + lcol;
  }

  floatx4 acc[4][4] = {};
  for (int k0 = 0; k0 < K; k0 += 32) {
    __syncthreads();
#pragma unroll
    for (int i = 0; i < 2; ++i) {
      int ch = wv * 2 + i;
      load_lds16(aptr[i] + k0, As + ch * 512);
      load_lds16(bptr[i] + k0, Bs + ch * 512);
    }
    __syncthreads();
    half8 a[4], b[4];
#pragma unroll
    for (int f = 0; f < 4; ++f) {
      a[f] = *(const half8*)(As + (wm * 64 + f * 16 + nn) * 32 + q * 8);
      b[f] = *(const half8*)(Bs + (wn * 64 + f * 16 + nn) * 32 + q * 8);
    }
#pragma unroll
    for (int fm = 0; fm < 4; ++fm)
#pragma unroll
      for (int fn = 0; fn < 4; ++fn)
        acc[fm][fn] = __builtin_amdgcn_mfma_f32_16x16x32_f16(a[fm], b[fn], acc[fm][fn], 0, 0, 0);
  }

  f16* gxd = gxc + (size_t)d * CHUNK * NB * NG;
#pragma unroll
  for (int fn = 0; fn < 4; ++fn) {
    int col = n0 + wn * 64 + fn * 16 + nn;
    float bv = bias[d * NG + col];
#pragma unroll
    for (int fm = 0; fm < 4; ++fm) {
      int mb = m0 + wm * 64 + fm * 16 + q * 4;
#pragma unroll
      for (int r = 0; r < 4; ++r)
        gxd[(size_t)(mb + r) * NG + col] = (f16)(acc[fm][fn][r] + bv);
    }
  }
}

// ---------------------------------------------------------------- recurrence (one chunk)
// 256 blocks = 8 groups x 32; group g = (dir=g&1, 16-row slice bsl=g>>1), closed
// under h dataflow. Sync = tagged-h words (epoch<<16 | f16 h) through the sc1
// coherent path. No barrier, no flags, no fences: blocks free-run, consumers
// poll their own operand words. ht layout: [parity][dir][row64][j512] u32.
__global__ __launch_bounds__(256, 1) void lstm_rec(
    const f16* __restrict__ gxc, const f16* __restrict__ whh,
    const int* __restrict__ lens, const int* __restrict__ cum,
    float* __restrict__ hsave, float* __restrict__ csave,
    unsigned* __restrict__ ht, f16* __restrict__ Y, float* __restrict__ outp,
    float* __restrict__ hT, float* __restrict__ cT,
    int c0, int mode, int layer) {
  const int tid = threadIdx.x, lane = tid & 63, wv = tid >> 6;
  const int g = blockIdx.x & 7, w = blockIdx.x >> 3;
  const int dir = g & 1, bsl = g >> 1;
  const int q = lane >> 4, nn = lane & 15;

  const int maxlen = lens[bsl * 16];  // rows sorted desc: uniform group exit
  int nst = maxlen - c0;
  if (nst <= 0) return;
  if (nst > CHUNK) nst = CHUNK;

  // LDS: double-buffered extracted-A tile (16 rows x 512 k f16, row pad +8)
  __shared__ __align__(16) unsigned As[2][16][260];
  __shared__ float s_g[4][16][17];

  const int jbase = w * 16 + wv * 4;
  const int coln = (nn >> 2) * NH + jbase + (nn & 3);
  const f16* whd = whh + (size_t)dir * NG * NH;
  half8 bf[16];
#pragma unroll
  for (int s = 0; s < 16; ++s)
    bf[s] = *(const half8*)(whd + (size_t)coln * NH + s * 32 + q * 8);

  const int b_e = bsl * 16 + nn;
  const int jglob = jbase + q;
  const int lene = lens[b_e];
  const int brow = bsl * 16 + q * 4;
  const int lidx = (dir * NB + b_e) * NH + jglob;
  float h = hsave[lidx], c = csave[lidx];

  const f16* gxd = gxc + (size_t)dir * CHUNK * NB * NG;
  const int ebase = layer * NT;  // epochs monotonic across chunks & layers

  for (int ct = 0; ct < nst; ++ct) {
    const int t = c0 + ct;
    const int e = ebase + t;      // tag required on consumed h
    const int par = t & 1;

    // gx loads issued early (HBM latency overlaps the poll)
    float gxv[4];
#pragma unroll
    for (int r = 0; r < 4; ++r)
      gxv[r] = (float)gxd[(size_t)(ct * NB + brow + r) * NG + coln];

    // ---- poll own k-quarter: wave wv covers k in [wv*128, wv*128+128) ----
    // lane (q,nn): row nn, words k = wv*128 + s*32 + q*8 .. +8
    const unsigned long long* p64 =
        (const unsigned long long*)(ht + ((size_t)(par * 2 + dir) * NB + bsl * 16 + nn) * NH +
                                    wv * 128 + q * 8);
    unsigned long long wb[4][4];
    bool done[4] = {false, false, false, false};
    int it = 0;
    for (;;) {
#pragma unroll
      for (int s = 0; s < 4; ++s)
        if (!done[s]) {
#pragma unroll
          for (int i = 0; i < 4; ++i)
            wb[s][i] = __hip_atomic_load(p64 + s * 16 + i, __ATOMIC_RELAXED,
                                         __HIP_MEMORY_SCOPE_AGENT);
          unsigned tg = 0xffffu;
#pragma unroll
          for (int i = 0; i < 4; ++i) {
            tg &= (unsigned)(wb[s][i] >> 16) & 0xffffu;
            tg &= (unsigned)(wb[s][i] >> 48);
          }
          // words hold only epoch e or e-2 (ping-pong parity); AND(e-2, e) < e,
          // AND(all e) == e -> exact freshness test.
          done[s] = (tg >= (unsigned)e);
        }
      bool ok = done[0] & done[1] & done[2] & done[3];
      if (__ballot(ok) == ~0ull) break;
      if (++it > 100000) break;  // fail as wrong-answer, not hang
    }

    // ---- extract f16 payloads -> LDS A tile ----
#pragma unroll
    for (int s = 0; s < 4; ++s) {
      unsigned d0 = (unsigned)(wb[s][0] & 0xffffu) | ((unsigned)(wb[s][0] >> 32) << 16);
      unsigned d1 = (unsigned)(wb[s][1] & 0xffffu) | ((unsigned)(wb[s][1] >> 32) << 16);
      unsigned d2 = (unsigned)(wb[s][2] & 0xffffu) | ((unsigned)(wb[s][2] >> 32) << 16);
      unsigned d3 = (unsigned)(wb[s][3] & 0xffffu) | ((unsigned)(wb[s][3] >> 32) << 16);
      *(u32x4*)&As[par][nn][wv * 64 + s * 16 + q * 4] = (u32x4){d0, d1, d2, d3};
    }
    __syncthreads();  // the ONLY per-step barrier (block-local)

    // ---- MFMA: 16 k-slabs from LDS ----
    floatx4 acc0 = {0.f, 0.f, 0.f, 0.f}, acc1 = {0.f, 0.f, 0.f, 0.f};
#pragma unroll
    for (int s = 0; s < 8; ++s) {
      half8 a0 = *(const half8*)&As[par][nn][(2 * s) * 16 + q * 4];
      half8 a1 = *(const half8*)&As[par][nn][(2 * s + 1) * 16 + q * 4];
      acc0 = __builtin_amdgcn_mfma_f32_16x16x32_f16(a0, bf[2 * s], acc0, 0, 0, 0);
      acc1 = __builtin_amdgcn_mfma_f32_16x16x32_f16(a1, bf[2 * s + 1], acc1, 0, 0, 0);
    }
#pragma unroll
    for (int r = 0; r < 4; ++r) s_g[wv][q * 4 + r][nn] = acc0[r] + acc1[r] + gxv[r];
    // s_g[wv] is wave-private: ds ordering (lgkmcnt) suffices, no barrier.

    const bool act = (t < lene);
    if (act) {
      float gi = s_g[wv][nn][q];
      float gf = s_g[wv][nn][4 + q];
      float gg = s_g[wv][nn][8 + q];
      float go = s_g[wv][nn][12 + q];
      c = sigf(gf) * c + sigf(gi) * tanhfast(gg);
      h = sigf(go) * tanhfast(c);
    }
    // ---- tagged publish (the sync) ----
    union { f16 f; unsigned short s; } hc; hc.f = (f16)h;
    unsigned word = ((unsigned)(e + 1) << 16) | hc.s;
    __hip_atomic_store(ht + ((size_t)(((t + 1) & 1) * 2 + dir) * NB + b_e) * NH + jglob,
                       word, __ATOMIC_RELAXED, __HIP_MEMORY_SCOPE_AGENT);
    // Y / packed-out stores: block-local until dispatch end, drain in poll shadow
    if (mode == 0) {
      int tp = act ? (dir ? (lene - 1 - t) : t) : t;
      Y[(size_t)(tp * NB + b_e) * (2 * NH) + dir * NH + jglob] = act ? (f16)h : (f16)0.f;
    } else if (act) {
      int tp = dir ? (lene - 1 - t) : t;
      outp[(size_t)(cum[tp] + b_e) * (2 * NH) + dir * NH + jglob] = h;
    }
  }

  hsave[lidx] = h;
  csave[lidx] = c;
  const int sidx = ((2 * layer + dir) * NB + b_e) * NH + jglob;
  hT[sidx] = h;
  cT[sidx] = c;
}

// ---------------------------------------------------------------- host
extern "C" void kernel_launch(void* const* d_in, const int* in_sizes, int n_in,
                              void* d_out, int out_size, void* d_ws, size_t ws_size,
                              hipStream_t stream) {
  const float* data  = (const float*)d_in[0];
  const float* h0    = (const float*)d_in[1];
  const float* c0    = (const float*)d_in[2];
  const float* w_ih0 = (const float*)d_in[3];
  const float* w_hh0 = (const float*)d_in[4];
  const float* b0    = (const float*)d_in[5];
  const float* w_ihr = (const float*)d_in[6];
  const float* w_hhr = (const float*)d_in[7];
  const float* b_r   = (const float*)d_in[8];
  const int* bs_raw  = (const int*)d_in[9];
  const int* pidx    = (const int*)d_in[10];
  const int nrows = in_sizes[0] / 512;
  float* out = (float*)d_out;

  // Y0 (layer-0 output, f16, 67MB) aliases d_out's packed-out region (dead by l2).
  f16* Y0 = (f16*)d_out;
  float* hT = out + (size_t)nrows * 1024;
  float* cT = hT + (size_t)6 * NB * NH;

  char* p = (char*)d_ws;
  auto take = [&](size_t bytes) {
    char* r = p;
    p += (bytes + 255) & ~(size_t)255;
    return (void*)r;
  };
  f16* gxc   = (f16*)take((size_t)2 * CHUNK * NB * NG * 2);  // 67 MB
  f16* Y1    = (f16*)take((size_t)NT * NB * 1024 * 2);       // 67 MB
  f16* X0    = Y1;  // alias: X0 dead after l0 gemm; Y1 first written by l1 rec
  f16* wih16 = (f16*)take((size_t)2 * NG * 1024 * 2);
  f16* whh16 = (f16*)take((size_t)2 * NG * NH * 2);
  unsigned* ht = (unsigned*)take((size_t)2 * 2 * NB * NH * 4);  // tagged h, 512KB
  float* hsave = (float*)take((size_t)2 * NB * NH * 4);
  float* csave = (float*)take((size_t)2 * NB * NH * 4);
  int* lens = (int*)take(256);
  int* cum  = (int*)take(NT * 4);

  prep_meta<<<1, 256, 0, stream>>>(bs_raw, lens, cum);
  (void)hipMemsetAsync(X0, 0, (size_t)NT * NB * 512 * 2, stream);
  (void)hipMemsetAsync(ht, 0, (size_t)2 * 2 * NB * NH * 4, stream);  // tags 0 (< any epoch)
  scatter_rows<<<nrows, 256, 0, stream>>>(data, pidx, X0);

  for (int l = 0; l < 3; ++l) {
    const float* wih_f = (l == 0) ? w_ih0 : w_ihr + (size_t)(l - 1) * 2 * NG * 1024;
    const float* whh_f = (l == 0) ? w_hh0 : w_hhr + (size_t)(l - 1) * 2 * NG * NH;
    const float* bias  = (l == 0) ? b0 : b_r + (size_t)(l - 1) * 2 * NG;
    const int K = (l == 0) ? 512 : 1024;
    const f16* Xl = (l == 0) ? X0 : ((l == 1) ? Y0 : Y1);
    f16* Yl = (l == 0) ? Y0 : Y1;
    f32_to_f16<<<256, 256, 0, stream>>>(wih_f, wih16, (size_t)2 * NG * K);
    f32_to_f16<<<256, 256, 0, stream>>>(whh_f, whh16, (size_t)2 * NG * NH);
    init_h<<<256, 256, 0, stream>>>(h0, c0, hsave, csave, ht, l);
    for (int c = 0; c < 4; ++c) {
      gemm_gx<<<dim3(16, 64, 2), 256, 0, stream>>>(Xl, wih16, bias, lens, gxc, K, c * CHUNK);
      lstm_rec<<<256, 256, 0, stream>>>(gxc, whh16, lens, cum, hsave, csave, ht, Yl,
                                        out, hT, cT, c * CHUNK, (l == 2) ? 1 : 0, l);
    }
  }
}